// Round 1
// baseline (429.565 us; speedup 1.0000x reference)
//
#include <hip/hip_runtime.h>
#include <hip/hip_bf16.h>

typedef short  short8  __attribute__((ext_vector_type(8)));
typedef short  short4v __attribute__((ext_vector_type(4)));
typedef float  f32x4   __attribute__((ext_vector_type(4)));

#define B_TOT 4096
#define SEQ   256
#define NDOF  7
#define HDIM  256
#define ROWS  16
#define DTF   0.002f

static __device__ __forceinline__ unsigned short f2bf(float f) {
    union { float f; unsigned u; } u; u.f = f;
    unsigned x = u.u;
    unsigned r = (x + 0x7FFFu + ((x >> 16) & 1u)) >> 16;   // RNE, inputs finite
    return (unsigned short)r;
}
static __device__ __forceinline__ unsigned pack2(float a, float b) {
    return (unsigned)f2bf(a) | ((unsigned)f2bf(b) << 16);
}
static __device__ __forceinline__ float silu(float p) {
    return p * __builtin_amdgcn_rcpf(1.0f + __expf(-p));
}

__global__ __launch_bounds__(256, 1)
void NeuralODE_kernel(const float* __restrict__ st0, const float* __restrict__ tq,
                      const float* __restrict__ W1,  const float* __restrict__ b1,
                      const float* __restrict__ W2,  const float* __restrict__ b2,
                      const float* __restrict__ W3,  const float* __restrict__ b3,
                      float* __restrict__ out)
{
    // LDS: h buffers padded to 264 elems/row (stride 528B -> 2-way max on b128 reads)
    __shared__ __align__(16) short h1b[16 * 264];
    __shared__ __align__(16) short h2b[16 * 264];
    __shared__ __align__(16) short taub[SEQ * 16 * 8];   // [s][n][8] bf16, d=7 is zero pad
    __shared__ __align__(16) short xbuf[4 * 16 * 40];    // per-wave x: [n][40] bf16 (k 0..31 + pad)

    const int tid  = threadIdx.x;
    const int w    = tid >> 6;
    const int lane = tid & 63;
    const int g    = lane >> 4;
    const int n    = lane & 15;
    const int b0   = blockIdx.x * ROWS;

    // ---------------- init: zero x buffers, fill tau cache ----------------
    for (int i = tid; i < 4 * 16 * 40; i += 256) xbuf[i] = 0;
    for (int i = tid; i < SEQ * ROWS; i += 256) taub[i * 8 + 7] = 0;   // pad lane d=7

    for (int it = tid; it < ROWS * SEQ * NDOF; it += 256) {
        int row = it / (SEQ * NDOF);
        int off = it - row * (SEQ * NDOF);
        int s   = off / NDOF;
        int d   = off - s * NDOF;
        float v = tq[(size_t)(b0 + row) * (SEQ * NDOF) + off];
        taub[s * 128 + row * 8 + d] = (short)f2bf(v);
    }

    // ---------------- weight fragments (register-stationary, transposed GEMM) ----
    // A layout (16x16x32): lane holds A[m=lane&15][k=8*(lane>>4)+j], j=0..7
    const int mbase = 64 * w;

    short8 a1f[4];
    short8 a2f[4][8];
    short8 a3f[8];
    f32x4  b1v[4], b2v[4], b3v;

#pragma unroll
    for (int t = 0; t < 4; ++t) {
        short8 fr;
#pragma unroll
        for (int j = 0; j < 8; ++j) {
            int k = 8 * g + j;   // padded x layout: 0-6=q,7=0,8-14=v,15=0,16-22=tau,23+=0
            int r = (k < 7) ? k : (k == 7 ? -1 : (k < 15 ? k - 1 : (k == 15 ? -1 : (k < 23 ? k - 2 : -1))));
            float v = (r >= 0) ? W1[r * HDIM + mbase + 16 * t + n] : 0.0f;
            fr[j] = (short)f2bf(v);
        }
        a1f[t] = fr;
    }
#pragma unroll
    for (int t = 0; t < 4; ++t) {
#pragma unroll
        for (int ks = 0; ks < 8; ++ks) {
            short8 fr;
#pragma unroll
            for (int j = 0; j < 8; ++j) {
                int k = 32 * ks + 8 * g + j;
                fr[j] = (short)f2bf(W2[(size_t)k * HDIM + mbase + 16 * t + n]);
            }
            a2f[t][ks] = fr;
        }
    }
#pragma unroll
    for (int ks = 0; ks < 8; ++ks) {
        short8 fr;
#pragma unroll
        for (int j = 0; j < 8; ++j) {
            int k = 32 * ks + 8 * g + j;
            fr[j] = (n < NDOF) ? (short)f2bf(W3[k * NDOF + n]) : (short)0;
        }
        a3f[ks] = fr;
    }
#pragma unroll
    for (int t = 0; t < 4; ++t) {
        int m = mbase + 16 * t + 4 * g;
        f32x4 t1; t1[0] = b1[m]; t1[1] = b1[m + 1]; t1[2] = b1[m + 2]; t1[3] = b1[m + 3];
        f32x4 t2; t2[0] = b2[m]; t2[1] = b2[m + 1]; t2[2] = b2[m + 2]; t2[3] = b2[m + 3];
        b1v[t] = t1; b2v[t] = t2;
    }
#pragma unroll
    for (int r = 0; r < 4; ++r) {
        int m = 4 * g + r;
        b3v[r] = (m < NDOF) ? b3[m] : 0.0f;
    }

    // ---------------- replicated per-wave state (lanes g<2 hold dofs m=4g+r) -----
    f32x4 qv, vv, av;
#pragma unroll
    for (int r = 0; r < 4; ++r) {
        int d = 4 * g + r;
        bool val = (g < 2) && (d < NDOF);
        qv[r] = val ? st0[(size_t)(b0 + n) * 14 + d] : 0.0f;
        vv[r] = val ? st0[(size_t)(b0 + n) * 14 + 7 + d] : 0.0f;
        av[r] = 0.0f;
    }

    __syncthreads();   // init fills visible

    short* xw = &xbuf[w * 640];

    auto write_x = [&](f32x4 qn, f32x4 vp, int sidx) {
        if (lane < 32) {
            short4v qs, vs;
            qs[0] = (short)f2bf(qn[0]); qs[1] = (short)f2bf(qn[1]);
            qs[2] = (short)f2bf(qn[2]); qs[3] = (short)f2bf(qn[3]);
            vs[0] = (short)f2bf(vp[0]); vs[1] = (short)f2bf(vp[1]);
            vs[2] = (short)f2bf(vp[2]); vs[3] = (short)f2bf(vp[3]);
            *(short4v*)&xw[n * 40 + 4 * g]      = qs;                       // k 0..7
            *(short4v*)&xw[n * 40 + 8 + 4 * g]  = vs;                       // k 8..15
            *(short4v*)&xw[n * 40 + 16 + 4 * g] =
                *(const short4v*)&taub[sidx * 128 + n * 8 + 4 * g];         // k 16..23
        }
    };

    auto accel = [&]() -> f32x4 {
        // L1: h1 = silu(x @ W1 + b1), computed as W1^T x^T, m-chunk 64 per wave
        short8 xf = *(const short8*)&xw[n * 40 + 8 * g];
        f32x4 c1[4];
#pragma unroll
        for (int t = 0; t < 4; ++t)
            c1[t] = __builtin_amdgcn_mfma_f32_16x16x32_bf16(a1f[t], xf, b1v[t], 0, 0, 0);
#pragma unroll
        for (int t = 0; t < 4; ++t) {
            unsigned d0 = pack2(silu(c1[t][0]), silu(c1[t][1]));
            unsigned d1 = pack2(silu(c1[t][2]), silu(c1[t][3]));
            int kk = 64 * w + 16 * t + 4 * g;
            ((unsigned*)h1b)[(n * 264 + kk) >> 1]     = d0;
            ((unsigned*)h1b)[(n * 264 + kk + 2) >> 1] = d1;
        }
        __syncthreads();   // B1

        // L2: h2 = silu(h1 @ W2 + b2)
        f32x4 c2[4];
#pragma unroll
        for (int t = 0; t < 4; ++t) c2[t] = b2v[t];
#pragma unroll
        for (int ks = 0; ks < 8; ++ks) {
            short8 bfr = *(const short8*)&h1b[n * 264 + 32 * ks + 8 * g];
#pragma unroll
            for (int t = 0; t < 4; ++t)
                c2[t] = __builtin_amdgcn_mfma_f32_16x16x32_bf16(a2f[t][ks], bfr, c2[t], 0, 0, 0);
        }
#pragma unroll
        for (int t = 0; t < 4; ++t) {
            unsigned d0 = pack2(silu(c2[t][0]), silu(c2[t][1]));
            unsigned d1 = pack2(silu(c2[t][2]), silu(c2[t][3]));
            int kk = 64 * w + 16 * t + 4 * g;
            ((unsigned*)h2b)[(n * 264 + kk) >> 1]     = d0;
            ((unsigned*)h2b)[(n * 264 + kk + 2) >> 1] = d1;
        }
        __syncthreads();   // B2

        // L3: a = h2 @ W3 + b3 (redundant full-K per wave; 2 accumulator chains)
        f32x4 c3a = b3v;
        f32x4 c3b; c3b[0] = 0.f; c3b[1] = 0.f; c3b[2] = 0.f; c3b[3] = 0.f;
#pragma unroll
        for (int ks = 0; ks < 4; ++ks) {
            short8 bfr = *(const short8*)&h2b[n * 264 + 32 * ks + 8 * g];
            c3a = __builtin_amdgcn_mfma_f32_16x16x32_bf16(a3f[ks], bfr, c3a, 0, 0, 0);
        }
#pragma unroll
        for (int ks = 4; ks < 8; ++ks) {
            short8 bfr = *(const short8*)&h2b[n * 264 + 32 * ks + 8 * g];
            c3b = __builtin_amdgcn_mfma_f32_16x16x32_bf16(a3f[ks], bfr, c3b, 0, 0, 0);
        }
        return c3a + c3b;
    };

    // ---------------- prologue: a0 = accel(t=0, initial_state), tau idx 0 --------
    write_x(qv, vv, 0);
    av = accel();

    // ---------------- 256 Verlet steps -------------------------------------------
    float* op = out + (size_t)(b0 + n) * SEQ * 14;

#pragma unroll 1
    for (int i = 0; i < SEQ; ++i) {
        f32x4 qn, vp;
#pragma unroll
        for (int r = 0; r < 4; ++r) {
            qn[r] = qv[r] + vv[r] * DTF + av[r] * (0.5f * DTF * DTF);
            vp[r] = vv[r] + av[r] * DTF;
        }

        // replicate reference's fp32 idx = floor(ts[i+1]/dt), IEEE division
        float tt = (float)(i + 1) * DTF;
        int sidx = (int)floorf(tt / DTF);
        sidx = (sidx > SEQ - 1) ? (SEQ - 1) : sidx;

        write_x(qn, vp, sidx);
        f32x4 an = accel();

#pragma unroll
        for (int r = 0; r < 4; ++r)
            vv[r] = vv[r] + 0.5f * (av[r] + an[r]) * DTF;
        qv = qn;
        av = an;

        if (w == 0 && lane < 32) {
            float* o = op + (size_t)i * 14;
#pragma unroll
            for (int r = 0; r < 4; ++r) {
                int d = 4 * g + r;
                if (d < NDOF) { o[d] = qn[r]; o[7 + d] = vv[r]; }
            }
        }
    }
}

extern "C" void kernel_launch(void* const* d_in, const int* in_sizes, int n_in,
                              void* d_out, int out_size, void* d_ws, size_t ws_size,
                              hipStream_t stream) {
    (void)in_sizes; (void)n_in; (void)d_ws; (void)ws_size; (void)out_size;
    const float* st0 = (const float*)d_in[0];
    const float* tq  = (const float*)d_in[1];
    const float* W1  = (const float*)d_in[2];
    const float* b1  = (const float*)d_in[3];
    const float* W2  = (const float*)d_in[4];
    const float* b2  = (const float*)d_in[5];
    const float* W3  = (const float*)d_in[6];
    const float* b3  = (const float*)d_in[7];

    NeuralODE_kernel<<<dim3(B_TOT / ROWS), dim3(256), 0, stream>>>(
        st0, tq, W1, b1, W2, b2, W3, b3, (float*)d_out);
}

// Round 2
// 346.802 us; speedup vs baseline: 1.2386x; 1.2386x over previous
//
#include <hip/hip_runtime.h>
#include <hip/hip_bf16.h>

typedef short    short8  __attribute__((ext_vector_type(8)));
typedef short    short4v __attribute__((ext_vector_type(4)));
typedef unsigned uint2v  __attribute__((ext_vector_type(2)));
typedef float    f32x4   __attribute__((ext_vector_type(4)));

#define B_TOT 4096
#define SEQ   256
#define NDOF  7
#define HDIM  256
#define ROWS  16
#define DTF   0.002f

// RNE float->bf16 (setup-time only; hot loop uses v_cvt_pk_bf16_f32)
static __device__ __forceinline__ unsigned short f2bf(float f) {
    union { float f; unsigned u; } u; u.f = f;
    unsigned x = u.u;
    unsigned r = (x + 0x7FFFu + ((x >> 16) & 1u)) >> 16;
    return (unsigned short)r;
}
static __device__ __forceinline__ unsigned cvt_pk_bf16(float lo, float hi) {
    unsigned r;
    asm("v_cvt_pk_bf16_f32 %0, %1, %2" : "=v"(r) : "v"(lo), "v"(hi));
    return r;
}
static __device__ __forceinline__ float silu(float p) {
    return p * __builtin_amdgcn_rcpf(1.0f + __expf(-p));
}

__global__ __launch_bounds__(512, 2)
void NeuralODE_kernel(const float* __restrict__ st0, const float* __restrict__ tq,
                      const float* __restrict__ W1,  const float* __restrict__ b1,
                      const float* __restrict__ W2,  const float* __restrict__ b2,
                      const float* __restrict__ W3,  const float* __restrict__ b3,
                      float* __restrict__ out)
{
    __shared__ __align__(16) short h1b[16 * 264];
    __shared__ __align__(16) short h2b[16 * 264];
    __shared__ __align__(16) short taub[SEQ * 16 * 8];   // [s][row][8] bf16, d=7 zero pad
    __shared__ __align__(16) short xbuf[8 * 16 * 40];    // per-wave x: [n][40] bf16
    __shared__ __align__(16) float red[4][16][12];       // L3 partials, stride 12 (bank spread)

    const int tid  = threadIdx.x;
    const int w    = tid >> 6;          // 8 waves
    const int lane = tid & 63;
    const int g    = lane >> 4;
    const int n    = lane & 15;
    const int b0   = blockIdx.x * ROWS;

    // ---------------- init: zero xbuf, fill tau cache -------------------------
    for (int i = tid; i < 8 * 16 * 40; i += 512) xbuf[i] = 0;
    for (int i = tid; i < SEQ * ROWS; i += 512) taub[i * 8 + 7] = 0;
    for (int it = tid; it < ROWS * SEQ * NDOF; it += 512) {
        int row = it / (SEQ * NDOF);
        int off = it - row * (SEQ * NDOF);
        int s   = off / NDOF;
        int d   = off - s * NDOF;
        taub[s * 128 + row * 8 + d] = (short)f2bf(tq[(size_t)(b0 + row) * (SEQ * NDOF) + off]);
    }

    // ---------------- weight fragments: m-chunk = 32 rows per wave ------------
    const int mb = 32 * w;

    // W1^T frags; bias b1 folded in at padded channel k==7 (x[7] is constant 1)
    short8 a1f[2];
#pragma unroll
    for (int t = 0; t < 2; ++t) {
        short8 fr;
#pragma unroll
        for (int j = 0; j < 8; ++j) {
            int k = 8 * g + j;   // x layout: 0-6=q, 7=1.0(bias), 8-14=v, 15=0, 16-22=tau, 23+=0
            int m = mb + 16 * t + n;
            float v;
            if (k < 7)       v = W1[k * HDIM + m];
            else if (k == 7) v = b1[m];
            else if (k < 15) v = W1[(k - 1) * HDIM + m];
            else if (k == 15) v = 0.0f;
            else if (k < 23) v = W1[(k - 2) * HDIM + m];
            else             v = 0.0f;
            fr[j] = (short)f2bf(v);
        }
        a1f[t] = fr;
    }
    short8 a2f[2][8];
#pragma unroll
    for (int t = 0; t < 2; ++t)
#pragma unroll
        for (int ks = 0; ks < 8; ++ks) {
            short8 fr;
#pragma unroll
            for (int j = 0; j < 8; ++j) {
                int k = 32 * ks + 8 * g + j;
                fr[j] = (short)f2bf(W2[(size_t)k * HDIM + mb + 16 * t + n]);
            }
            a2f[t][ks] = fr;
        }
    // W3^T frags: waves 0..3 own K-chunk [64w, 64w+64)
    short8 a3f[2] = {};
    if (w < 4) {
#pragma unroll
        for (int s = 0; s < 2; ++s) {
            short8 fr;
#pragma unroll
            for (int j = 0; j < 8; ++j) {
                int k = 64 * w + 32 * s + 8 * g + j;
                fr[j] = (n < NDOF) ? (short)f2bf(W3[k * NDOF + n]) : (short)0;
            }
            a3f[s] = fr;
        }
    }
    f32x4 b2v[2];
#pragma unroll
    for (int t = 0; t < 2; ++t) {
        int m = mb + 16 * t + 4 * g;
        f32x4 tv; tv[0] = b2[m]; tv[1] = b2[m + 1]; tv[2] = b2[m + 2]; tv[3] = b2[m + 3];
        b2v[t] = tv;
    }
    f32x4 b3v;
#pragma unroll
    for (int r = 0; r < 4; ++r) {
        int m = 4 * g + r;
        b3v[r] = (m < NDOF) ? b3[m] : 0.0f;
    }

    // ---------------- replicated state (g<2 lanes hold dofs d=4g+r) -----------
    f32x4 qv, vv, av;
#pragma unroll
    for (int r = 0; r < 4; ++r) {
        int d = 4 * g + r;
        bool val = (g < 2) && (d < NDOF);
        qv[r] = val ? st0[(size_t)(b0 + n) * 14 + d]
                    : ((g == 1 && r == 3) ? 1.0f : 0.0f);   // x[7]=1 bias channel
        vv[r] = val ? st0[(size_t)(b0 + n) * 14 + 7 + d] : 0.0f;
        av[r] = 0.0f;
    }

    __syncthreads();   // init visible

    short* xw = &xbuf[w * 640];

    auto write_x = [&](f32x4 qn, f32x4 vp, int sidx) {
        if (lane < 32) {
            uint2v qp, vq;
            qp[0] = cvt_pk_bf16(qn[0], qn[1]); qp[1] = cvt_pk_bf16(qn[2], qn[3]);
            vq[0] = cvt_pk_bf16(vp[0], vp[1]); vq[1] = cvt_pk_bf16(vp[2], vp[3]);
            *(uint2v*)&xw[n * 40 + 4 * g]       = qp;                        // k 0..7
            *(uint2v*)&xw[n * 40 + 8 + 4 * g]   = vq;                        // k 8..15
            *(short4v*)&xw[n * 40 + 16 + 4 * g] =
                *(const short4v*)&taub[sidx * 128 + n * 8 + 4 * g];          // k 16..23
        }
    };

    auto accel = [&]() -> f32x4 {
        const f32x4 cz = {0.0f, 0.0f, 0.0f, 0.0f};
        // L1 (bias folded into W1 via x[7]=1)
        short8 xf = *(const short8*)&xw[n * 40 + 8 * g];
        f32x4 c1[2];
#pragma unroll
        for (int t = 0; t < 2; ++t)
            c1[t] = __builtin_amdgcn_mfma_f32_16x16x32_bf16(a1f[t], xf, cz, 0, 0, 0);
#pragma unroll
        for (int t = 0; t < 2; ++t) {
            uint2v p;
            p[0] = cvt_pk_bf16(silu(c1[t][0]), silu(c1[t][1]));
            p[1] = cvt_pk_bf16(silu(c1[t][2]), silu(c1[t][3]));
            *(uint2v*)&h1b[n * 264 + mb + 16 * t + 4 * g] = p;
        }
        __syncthreads();   // B1

        // L2
        f32x4 c2a = b2v[0], c2b = b2v[1];
#pragma unroll
        for (int ks = 0; ks < 8; ++ks) {
            short8 bfr = *(const short8*)&h1b[n * 264 + 32 * ks + 8 * g];
            c2a = __builtin_amdgcn_mfma_f32_16x16x32_bf16(a2f[0][ks], bfr, c2a, 0, 0, 0);
            c2b = __builtin_amdgcn_mfma_f32_16x16x32_bf16(a2f[1][ks], bfr, c2b, 0, 0, 0);
        }
        {
            uint2v p;
            p[0] = cvt_pk_bf16(silu(c2a[0]), silu(c2a[1]));
            p[1] = cvt_pk_bf16(silu(c2a[2]), silu(c2a[3]));
            *(uint2v*)&h2b[n * 264 + mb + 4 * g] = p;
            p[0] = cvt_pk_bf16(silu(c2b[0]), silu(c2b[1]));
            p[1] = cvt_pk_bf16(silu(c2b[2]), silu(c2b[3]));
            *(uint2v*)&h2b[n * 264 + mb + 16 + 4 * g] = p;
        }
        __syncthreads();   // B2

        // L3: waves 0..3 compute K-chunk partials
        if (w < 4) {
            short8 p0 = *(const short8*)&h2b[n * 264 + 64 * w + 8 * g];
            short8 p1 = *(const short8*)&h2b[n * 264 + 64 * w + 32 + 8 * g];
            f32x4 c3 = __builtin_amdgcn_mfma_f32_16x16x32_bf16(a3f[0], p0, cz, 0, 0, 0);
            c3 = __builtin_amdgcn_mfma_f32_16x16x32_bf16(a3f[1], p1, c3, 0, 0, 0);
            if (g < 2) *(f32x4*)&red[w][n][4 * g] = c3;
        }
        __syncthreads();   // B3

        // all waves reduce the 4 partials (g>=2 lanes compute don't-care values)
        const float* rp = &red[0][0][0];
        int ro = n * 12 + 4 * (g & 1);
        f32x4 s0 = *(const f32x4*)(rp + ro)       + *(const f32x4*)(rp + 192 + ro);
        f32x4 s1 = *(const f32x4*)(rp + 384 + ro) + *(const f32x4*)(rp + 576 + ro);
        return (s0 + s1) + b3v;
    };

    // ---------------- prologue: a0 = accel(t=0, initial_state), tau idx 0 -----
    write_x(qv, vv, 0);
    av = accel();

    // ---------------- 256 Verlet steps ----------------------------------------
    float* op = out + (size_t)(b0 + n) * SEQ * 14;

#pragma unroll 1
    for (int i = 0; i < SEQ; ++i) {
        f32x4 qn, vp;
#pragma unroll
        for (int r = 0; r < 4; ++r) {
            qn[r] = qv[r] + vv[r] * DTF + av[r] * (0.5f * DTF * DTF);
            vp[r] = vv[r] + av[r] * DTF;
        }

        // replicate reference fp32 idx = floor(ts[i+1]/dt), clipped
        float tt = (float)(i + 1) * DTF;
        int sidx = (int)floorf(tt / DTF);
        sidx = (sidx > SEQ - 1) ? (SEQ - 1) : sidx;

        write_x(qn, vp, sidx);
        f32x4 an = accel();

#pragma unroll
        for (int r = 0; r < 4; ++r)
            vv[r] = vv[r] + 0.5f * (av[r] + an[r]) * DTF;
        qv = qn;
        av = an;

        if (w == 0 && lane < 32) {
            float* o = op + (size_t)i * 14;
#pragma unroll
            for (int r = 0; r < 4; ++r) {
                int d = 4 * g + r;
                if (d < NDOF) { o[d] = qn[r]; o[7 + d] = vv[r]; }
            }
        }
    }
}

extern "C" void kernel_launch(void* const* d_in, const int* in_sizes, int n_in,
                              void* d_out, int out_size, void* d_ws, size_t ws_size,
                              hipStream_t stream) {
    (void)in_sizes; (void)n_in; (void)d_ws; (void)ws_size; (void)out_size;
    const float* st0 = (const float*)d_in[0];
    const float* tq  = (const float*)d_in[1];
    const float* W1  = (const float*)d_in[2];
    const float* b1  = (const float*)d_in[3];
    const float* W2  = (const float*)d_in[4];
    const float* b2  = (const float*)d_in[5];
    const float* W3  = (const float*)d_in[6];
    const float* b3  = (const float*)d_in[7];

    NeuralODE_kernel<<<dim3(B_TOT / ROWS), dim3(512), 0, stream>>>(
        st0, tq, W1, b1, W2, b2, W3, b3, (float*)d_out);
}